// Round 15
// baseline (103.549 us; speedup 1.0000x reference)
//
#include <hip/hip_runtime.h>
#include <math.h>

#define DIM 256
#define KCODES 1024
#define NTILE 64   // 16-code tiles
#define BM 256     // rows per block (4 waves x 64 rows)
#define ESCALE 512.0f

typedef long i64;
typedef __attribute__((ext_vector_type(2))) long i64x2;
typedef __attribute__((ext_vector_type(4))) float f32x4;

// ---------------------------------------------------------------------------
// Prep: enormh[k] = -ESCALE*||e_k||^2/2, codebook scaled x512 -> fp8 e4m3 in
// MFMA B-fragment order:
// byte = (k>>4)*4096 + (ks>>1)*1024 + (lk*16+(k&15))*16 + (ks&1)*8 + (d&7)
// ---------------------------------------------------------------------------
__global__ __launch_bounds__(64) void vq_prep_kernel(
    const float* __restrict__ E, float* __restrict__ enormh,
    unsigned char* __restrict__ Ef8) {
  const int k = blockIdx.x;   // code
  const int t = threadIdx.x;  // dims 4t..4t+3
  const float4 v = *reinterpret_cast<const float4*>(&E[k * DIM + t * 4]);
  const int d0 = t * 4;
  const int ks = d0 >> 5;
  const int lk = (d0 >> 3) & 3;
  const int j = d0 & 7;  // 0 or 4
  const int lane16 = lk * 16 + (k & 15);
  const size_t byte = (size_t)((k >> 4) * 4096) + (size_t)((ks >> 1) * 1024) +
                      (size_t)(lane16 * 16) + (size_t)((ks & 1) * 8 + j);
  int p = __builtin_amdgcn_cvt_pk_fp8_f32(v.x * ESCALE, v.y * ESCALE, 0, 0);
  p = __builtin_amdgcn_cvt_pk_fp8_f32(v.z * ESCALE, v.w * ESCALE, p, 1);
  *reinterpret_cast<unsigned int*>(Ef8 + byte) = (unsigned int)p;
  float s = v.x * v.x + v.y * v.y + v.z * v.z + v.w * v.w;
#pragma unroll
  for (int off = 32; off >= 1; off >>= 1) s += __shfl_down(s, off);
  if (t == 0) enormh[k] = -0.5f * ESCALE * s;
}

__device__ inline i64 pack_fp8x8(const float4& a, const float4& b) {
  int lo = __builtin_amdgcn_cvt_pk_fp8_f32(a.x, a.y, 0, 0);
  lo = __builtin_amdgcn_cvt_pk_fp8_f32(a.z, a.w, lo, 1);
  int hi = __builtin_amdgcn_cvt_pk_fp8_f32(b.x, b.y, 0, 0);
  hi = __builtin_amdgcn_cvt_pk_fp8_f32(b.z, b.w, hi, 1);
  return ((i64)(unsigned int)hi << 32) | (i64)(unsigned int)lo;
}

// ---------------------------------------------------------------------------
// Fused main v15: barrier-free fp8 register pipeline at 64 ROWS/WAVE.
// 256 rows/block, 256 thr = 4 independent waves; wave w owns rows
// [w*64,w*64+64) x ALL 1024 codes. Per tile: 32 MFMAs in 4 interleaved acc
// chains (dep distance 4) ~400 issue-cycles -> the 2-tile-ahead prefetch
// window (~800 cyc) exceeds L2 latency; stalls vanish without TLP. Total
// L2 B-traffic halves vs v13 (256 MB). 1 block/CU, VGPR ~170 under (256,1).
// ---------------------------------------------------------------------------
__global__ __launch_bounds__(256, 1) void vq_fused_kernel(
    const float* __restrict__ X, const float* __restrict__ E,
    const unsigned char* __restrict__ Ef8, const float* __restrict__ enormh,
    float* __restrict__ outq, float* __restrict__ partials) {
  __shared__ int idxs[BM];
  __shared__ float lred[4];

  const int tid = threadIdx.x;
  const int w = tid >> 6;  // wave 0..3 -> rows w*64 .. w*64+63
  const int lane = tid & 63;
  const int lr = lane & 15;
  const int lk = lane >> 4;
  const int row0 = blockIdx.x * BM;

  // ---- A: 64 rows x 256 dims per wave, fp32 -> fp8 fragments (64 VGPRs)
  i64 Af[4][8];
#pragma unroll
  for (int mt = 0; mt < 4; ++mt) {
    const float* xrow = &X[(size_t)(row0 + w * 64 + mt * 16 + lr) * DIM];
#pragma unroll
    for (int ks = 0; ks < 8; ++ks) {
      const int k0 = ks * 32 + lk * 8;
      const float4 a = *reinterpret_cast<const float4*>(&xrow[k0]);
      const float4 b = *reinterpret_cast<const float4*>(&xrow[k0 + 4]);
      Af[mt][ks] = pack_fp8x8(a, b);
    }
  }

  float maxv[16];
  int mini[16];
#pragma unroll
  for (int i = 0; i < 16; ++i) { maxv[i] = -INFINITY; mini[i] = 0; }

  const char* efbase = reinterpret_cast<const char*>(Ef8) + lane * 16;

  // ---- named register double-buffer: tile = 4 x i64x2 (16 VGPRs each),
  // plus the tile's enorm value in the same 2-tile-ahead prefetch window
  i64x2 B0[4], B1[4];
  float en0, en1;
#pragma unroll
  for (int p = 0; p < 4; ++p)
    B0[p] = *reinterpret_cast<const i64x2*>(efbase + p * 1024);
#pragma unroll
  for (int p = 0; p < 4; ++p)
    B1[p] = *reinterpret_cast<const i64x2*>(efbase + 4096 + p * 1024);
  en0 = enormh[lr];
  en1 = enormh[16 + lr];

  // 32 MFMAs/tile in 4 interleaved acc chains (dep distance 4)
#define COMPUTE_TILE(BUF)                                                     \
  {                                                                           \
    _Pragma("unroll") for (int p = 0; p < 4; ++p) {                           \
      _Pragma("unroll") for (int half = 0; half < 2; ++half) {                \
        _Pragma("unroll") for (int mt = 0; mt < 4; ++mt) {                    \
          acc[mt] = __builtin_amdgcn_mfma_f32_16x16x32_fp8_fp8(               \
              Af[mt][2 * p + half], BUF[p][half], acc[mt], 0, 0, 0);          \
        }                                                                     \
      }                                                                       \
    }                                                                         \
  }

#define RELOAD(BUF, EN, TILE)                                                 \
  {                                                                           \
    const char* nsrc = efbase + (size_t)(TILE) * 4096;                        \
    _Pragma("unroll") for (int p = 0; p < 4; ++p) BUF[p] =                    \
        *reinterpret_cast<const i64x2*>(nsrc + p * 1024);                     \
    EN = enormh[(TILE) * 16 + lr];                                            \
  }

#pragma unroll
  for (int t = 0; t < NTILE; ++t) {
    f32x4 acc[4];
    if (t & 1) {
#pragma unroll
      for (int mt = 0; mt < 4; ++mt) {
        acc[mt][0] = en1; acc[mt][1] = en1; acc[mt][2] = en1; acc[mt][3] = en1;
      }
      COMPUTE_TILE(B1);
      if (t + 2 < NTILE) RELOAD(B1, en1, t + 2);
    } else {
#pragma unroll
      for (int mt = 0; mt < 4; ++mt) {
        acc[mt][0] = en0; acc[mt][1] = en0; acc[mt][2] = en0; acc[mt][3] = en0;
      }
      COMPUTE_TILE(B0);
      if (t + 2 < NTILE) RELOAD(B0, en0, t + 2);
    }
    const int code = t * 16 + lr;  // ascending per lane -> first occurrence
#pragma unroll
    for (int mt = 0; mt < 4; ++mt)
#pragma unroll
      for (int r = 0; r < 4; ++r) {
        const float s = acc[mt][r];
        const int ri = mt * 4 + r;  // row w*64 + mt*16 + lk*4 + r
        if (s > maxv[ri]) { maxv[ri] = s; mini[ri] = code; }
      }
  }
#undef COMPUTE_TILE
#undef RELOAD

  // reduce across the 16 code-lanes (lr); max score, tie -> lower code
#pragma unroll
  for (int off = 1; off < 16; off <<= 1) {
#pragma unroll
    for (int ri = 0; ri < 16; ++ri) {
      const float ov = __shfl_xor(maxv[ri], off);
      const int oi = __shfl_xor(mini[ri], off);
      if (ov > maxv[ri] || (ov == maxv[ri] && oi < mini[ri])) {
        maxv[ri] = ov; mini[ri] = oi;
      }
    }
  }
  if (lr == 0) {
#pragma unroll
    for (int mt = 0; mt < 4; ++mt)
#pragma unroll
      for (int r = 0; r < 4; ++r)
        idxs[w * 64 + mt * 16 + lk * 4 + r] = mini[mt * 4 + r];
  }
  __syncthreads();

  // ---- fused epilogue: gather + STE + loss partial, exact fp32.
  // 4 passes of 64 rows; 4 threads per row, 64 dims each, coalesced float4.
  float lsum = 0.0f;
#pragma unroll
  for (int q = 0; q < 4; ++q) {
    const int er = q * 64 + (tid >> 2);
    const int eq = tid & 3;
    const int code = idxs[er];
    const float* erow = &E[(size_t)code * DIM];
    const float* xrow = &X[(size_t)(row0 + er) * DIM];
    float* orow = &outq[(size_t)(row0 + er) * DIM];
#pragma unroll
    for (int j = 0; j < 16; ++j) {
      const int d = j * 16 + eq * 4;
      const float4 e = *reinterpret_cast<const float4*>(&erow[d]);
      const float4 x = *reinterpret_cast<const float4*>(&xrow[d]);
      const float dx0 = e.x - x.x, dx1 = e.y - x.y;
      const float dx2 = e.z - x.z, dx3 = e.w - x.w;
      float4 o;
      o.x = x.x + dx0; o.y = x.y + dx1; o.z = x.z + dx2; o.w = x.w + dx3;
      *reinterpret_cast<float4*>(&orow[d]) = o;
      lsum += dx0 * dx0 + dx1 * dx1 + dx2 * dx2 + dx3 * dx3;
    }
  }
#pragma unroll
  for (int off = 32; off >= 1; off >>= 1) lsum += __shfl_down(lsum, off);
  if (lane == 0) lred[w] = lsum;
  __syncthreads();
  if (tid == 0)
    partials[blockIdx.x] = lred[0] + lred[1] + lred[2] + lred[3];
}

// ---------------------------------------------------------------------------
// Deterministic loss reduction
// ---------------------------------------------------------------------------
__global__ __launch_bounds__(256) void vq_finalize_kernel(
    const float* __restrict__ partials, float* __restrict__ out_loss,
    int nparts, float inv_count) {
  const int tid = threadIdx.x;
  float s = 0.0f;
  for (int i = tid; i < nparts; i += 256) s += partials[i];
#pragma unroll
  for (int off = 32; off >= 1; off >>= 1) s += __shfl_down(s, off);
  __shared__ float w[4];
  if ((tid & 63) == 0) w[tid >> 6] = s;
  __syncthreads();
  if (tid == 0) {
    const float m = (w[0] + w[1] + w[2] + w[3]) * inv_count;
    out_loss[0] = m + 0.25f * m;  // q_latent + commitment * e_latent
  }
}

extern "C" void kernel_launch(void* const* d_in, const int* in_sizes, int n_in,
                              void* d_out, int out_size, void* d_ws,
                              size_t ws_size, hipStream_t stream) {
  const float* X = (const float*)d_in[0];  // [16,4096,256] fp32
  const float* E = (const float*)d_in[1];  // [1024,256] fp32
  float* out = (float*)d_out;              // [0]=loss, [1..]=quantized

  char* ws = (char*)d_ws;
  float* enormh = (float*)ws;                             // @0KB
  float* partials = (float*)(ws + 16 * 1024);             // @16KB
  unsigned char* Ef8 = (unsigned char*)(ws + 48 * 1024);  // @48KB (256KB)

  const int nrows = in_sizes[0] / DIM;  // 65536
  const int nb_main = nrows / BM;       // 256

  vq_prep_kernel<<<KCODES, 64, 0, stream>>>(E, enormh, Ef8);
  vq_fused_kernel<<<nb_main, 256, 0, stream>>>(X, E, Ef8, enormh, out + 1,
                                               partials);
  vq_finalize_kernel<<<1, 256, 0, stream>>>(partials, out, nb_main,
                                            1.0f / (float)in_sizes[0]);
}

// Round 16
// 75.840 us; speedup vs baseline: 1.3654x; 1.3654x over previous
//
#include <hip/hip_runtime.h>
#include <math.h>

#define DIM 256
#define KCODES 1024
#define NT2 32     // 16-code tiles per wave (half the codebook)
#define BM 128     // rows per block (4 row-groups x 32 rows)
#define ESCALE 512.0f

typedef long i64;
typedef __attribute__((ext_vector_type(2))) long i64x2;
typedef __attribute__((ext_vector_type(4))) float f32x4;

// ---------------------------------------------------------------------------
// Prep: enormh[k] = -ESCALE*||e_k||^2/2, codebook scaled x512 -> fp8 e4m3 in
// MFMA B-fragment order:
// byte = (k>>4)*4096 + (ks>>1)*1024 + (lk*16+(k&15))*16 + (ks&1)*8 + (d&7)
// ---------------------------------------------------------------------------
__global__ __launch_bounds__(64) void vq_prep_kernel(
    const float* __restrict__ E, float* __restrict__ enormh,
    unsigned char* __restrict__ Ef8) {
  const int k = blockIdx.x;   // code
  const int t = threadIdx.x;  // dims 4t..4t+3
  const float4 v = *reinterpret_cast<const float4*>(&E[k * DIM + t * 4]);
  const int d0 = t * 4;
  const int ks = d0 >> 5;
  const int lk = (d0 >> 3) & 3;
  const int j = d0 & 7;  // 0 or 4
  const int lane16 = lk * 16 + (k & 15);
  const size_t byte = (size_t)((k >> 4) * 4096) + (size_t)((ks >> 1) * 1024) +
                      (size_t)(lane16 * 16) + (size_t)((ks & 1) * 8 + j);
  int p = __builtin_amdgcn_cvt_pk_fp8_f32(v.x * ESCALE, v.y * ESCALE, 0, 0);
  p = __builtin_amdgcn_cvt_pk_fp8_f32(v.z * ESCALE, v.w * ESCALE, p, 1);
  *reinterpret_cast<unsigned int*>(Ef8 + byte) = (unsigned int)p;
  float s = v.x * v.x + v.y * v.y + v.z * v.z + v.w * v.w;
#pragma unroll
  for (int off = 32; off >= 1; off >>= 1) s += __shfl_down(s, off);
  if (t == 0) enormh[k] = -0.5f * ESCALE * s;
}

__device__ inline i64 pack_fp8x8(const float4& a, const float4& b) {
  int lo = __builtin_amdgcn_cvt_pk_fp8_f32(a.x, a.y, 0, 0);
  lo = __builtin_amdgcn_cvt_pk_fp8_f32(a.z, a.w, lo, 1);
  int hi = __builtin_amdgcn_cvt_pk_fp8_f32(b.x, b.y, 0, 0);
  hi = __builtin_amdgcn_cvt_pk_fp8_f32(b.z, b.w, hi, 1);
  return ((i64)(unsigned int)hi << 32) | (i64)(unsigned int)lo;
}

// ---------------------------------------------------------------------------
// Fused main v16: v13's per-wave pipeline (32 rows/wave, 170-cyc tile window,
// barrier-free fp8 reg double-buffer) at 4 waves/SIMD via CODE-SPACE SPLIT:
// 512 thr = 8 waves; wave w = (row-group w&3, code-half w>>2). Each wave
// scans 32 rows x 512 codes; halves merged in LDS (half0 has lower indices,
// tie logic preserves first occurrence). Grid 512 -> 16 waves/CU.
// MFMA order = dep-distance-2 (alternate mt chains).
// ---------------------------------------------------------------------------
__global__ __launch_bounds__(512) void vq_fused_kernel(
    const float* __restrict__ X, const float* __restrict__ E,
    const unsigned char* __restrict__ Ef8, const float* __restrict__ enormh,
    float* __restrict__ outq, float* __restrict__ partials) {
  __shared__ float fval_s[2][BM];
  __shared__ int fidx_s[2][BM];
  __shared__ int idxs[BM];
  __shared__ float lred[8];

  const int tid = threadIdx.x;
  const int w = tid >> 6;   // wave 0..7
  const int lane = tid & 63;
  const int lr = lane & 15;
  const int lk = lane >> 4;
  const int rg = w & 3;     // row-group: rows rg*32 .. rg*32+31
  const int ch = w >> 2;    // code-half: tiles ch*32 .. ch*32+31
  const int row0 = blockIdx.x * BM;

  // ---- A: 32 rows x 256 dims per wave, fp32 -> fp8 fragments (32 VGPRs)
  i64 Af[2][8];
#pragma unroll
  for (int mt = 0; mt < 2; ++mt) {
    const float* xrow = &X[(size_t)(row0 + rg * 32 + mt * 16 + lr) * DIM];
#pragma unroll
    for (int ks = 0; ks < 8; ++ks) {
      const int k0 = ks * 32 + lk * 8;
      const float4 a = *reinterpret_cast<const float4*>(&xrow[k0]);
      const float4 b = *reinterpret_cast<const float4*>(&xrow[k0 + 4]);
      Af[mt][ks] = pack_fp8x8(a, b);
    }
  }

  float maxv[8];
  int mini[8];
#pragma unroll
  for (int i = 0; i < 8; ++i) { maxv[i] = -INFINITY; mini[i] = 0; }

  // this wave's tile range starts at global tile ch*32
  const char* efbase =
      reinterpret_cast<const char*>(Ef8) + (size_t)ch * 32 * 4096 + lane * 16;
  const float* enh_base = enormh + ch * 512;

  // ---- named register double-buffer: tile = 4 x i64x2, 2-tile-ahead window
  i64x2 B0[4], B1[4];
  float en0, en1;
#pragma unroll
  for (int p = 0; p < 4; ++p)
    B0[p] = *reinterpret_cast<const i64x2*>(efbase + p * 1024);
#pragma unroll
  for (int p = 0; p < 4; ++p)
    B1[p] = *reinterpret_cast<const i64x2*>(efbase + 4096 + p * 1024);
  en0 = enh_base[lr];
  en1 = enh_base[16 + lr];

  // dep-distance-2: alternate mt between consecutive MFMAs on each chain
#define COMPUTE_TILE(BUF)                                                     \
  {                                                                           \
    _Pragma("unroll") for (int p = 0; p < 4; ++p) {                           \
      _Pragma("unroll") for (int half = 0; half < 2; ++half) {                \
        _Pragma("unroll") for (int mt = 0; mt < 2; ++mt) {                    \
          acc[mt] = __builtin_amdgcn_mfma_f32_16x16x32_fp8_fp8(               \
              Af[mt][2 * p + half], BUF[p][half], acc[mt], 0, 0, 0);          \
        }                                                                     \
      }                                                                       \
    }                                                                         \
  }

#define RELOAD(BUF, EN, TILE)                                                 \
  {                                                                           \
    const char* nsrc = efbase + (size_t)(TILE) * 4096;                        \
    _Pragma("unroll") for (int p = 0; p < 4; ++p) BUF[p] =                    \
        *reinterpret_cast<const i64x2*>(nsrc + p * 1024);                     \
    EN = enh_base[(TILE) * 16 + lr];                                          \
  }

#pragma unroll
  for (int t = 0; t < NT2; ++t) {
    f32x4 acc[2];
    if (t & 1) {
#pragma unroll
      for (int mt = 0; mt < 2; ++mt) {
        acc[mt][0] = en1; acc[mt][1] = en1; acc[mt][2] = en1; acc[mt][3] = en1;
      }
      COMPUTE_TILE(B1);
      if (t + 2 < NT2) RELOAD(B1, en1, t + 2);
    } else {
#pragma unroll
      for (int mt = 0; mt < 2; ++mt) {
        acc[mt][0] = en0; acc[mt][1] = en0; acc[mt][2] = en0; acc[mt][3] = en0;
      }
      COMPUTE_TILE(B0);
      if (t + 2 < NT2) RELOAD(B0, en0, t + 2);
    }
    const int code = (ch * 32 + t) * 16 + lr;  // ascending per lane
#pragma unroll
    for (int mt = 0; mt < 2; ++mt)
#pragma unroll
      for (int r = 0; r < 4; ++r) {
        const float s = acc[mt][r];
        const int ri = mt * 4 + r;  // row rg*32 + mt*16 + lk*4 + r
        if (s > maxv[ri]) { maxv[ri] = s; mini[ri] = code; }
      }
  }
#undef COMPUTE_TILE
#undef RELOAD

  // reduce across the 16 code-lanes (lr); max score, tie -> lower code
#pragma unroll
  for (int off = 1; off < 16; off <<= 1) {
#pragma unroll
    for (int ri = 0; ri < 8; ++ri) {
      const float ov = __shfl_xor(maxv[ri], off);
      const int oi = __shfl_xor(mini[ri], off);
      if (ov > maxv[ri] || (ov == maxv[ri] && oi < mini[ri])) {
        maxv[ri] = ov; mini[ri] = oi;
      }
    }
  }
  if (lr == 0) {
#pragma unroll
    for (int mt = 0; mt < 2; ++mt)
#pragma unroll
      for (int r = 0; r < 4; ++r) {
        fval_s[ch][rg * 32 + mt * 16 + lk * 4 + r] = maxv[mt * 4 + r];
        fidx_s[ch][rg * 32 + mt * 16 + lk * 4 + r] = mini[mt * 4 + r];
      }
  }
  __syncthreads();
  if (tid < BM) {
    float bv = fval_s[0][tid];
    int bi = fidx_s[0][tid];
    const float v1 = fval_s[1][tid];
    const int i1 = fidx_s[1][tid];
    if (v1 > bv || (v1 == bv && i1 < bi)) { bv = v1; bi = i1; }
    idxs[tid] = bi;
  }
  __syncthreads();

  // ---- fused epilogue: gather + STE + loss partial, exact fp32.
  // 4 threads per row x 128 rows = 512 threads, coalesced float4.
  const int er = tid >> 2;  // row 0..127
  const int eq = tid & 3;
  const int code = idxs[er];
  const float* erow = &E[(size_t)code * DIM];
  const float* xrow = &X[(size_t)(row0 + er) * DIM];
  float* orow = &outq[(size_t)(row0 + er) * DIM];
  float lsum = 0.0f;
#pragma unroll
  for (int j = 0; j < 16; ++j) {
    const int d = j * 16 + eq * 4;
    const float4 e = *reinterpret_cast<const float4*>(&erow[d]);
    const float4 x = *reinterpret_cast<const float4*>(&xrow[d]);
    const float dx0 = e.x - x.x, dx1 = e.y - x.y;
    const float dx2 = e.z - x.z, dx3 = e.w - x.w;
    float4 o;
    o.x = x.x + dx0; o.y = x.y + dx1; o.z = x.z + dx2; o.w = x.w + dx3;
    *reinterpret_cast<float4*>(&orow[d]) = o;
    lsum += dx0 * dx0 + dx1 * dx1 + dx2 * dx2 + dx3 * dx3;
  }
#pragma unroll
  for (int off = 32; off >= 1; off >>= 1) lsum += __shfl_down(lsum, off);
  if (lane == 0) lred[w] = lsum;
  __syncthreads();
  if (tid == 0) {
    float s = 0.0f;
#pragma unroll
    for (int i = 0; i < 8; ++i) s += lred[i];
    partials[blockIdx.x] = s;
  }
}

// ---------------------------------------------------------------------------
// Deterministic loss reduction
// ---------------------------------------------------------------------------
__global__ __launch_bounds__(256) void vq_finalize_kernel(
    const float* __restrict__ partials, float* __restrict__ out_loss,
    int nparts, float inv_count) {
  const int tid = threadIdx.x;
  float s = 0.0f;
  for (int i = tid; i < nparts; i += 256) s += partials[i];
#pragma unroll
  for (int off = 32; off >= 1; off >>= 1) s += __shfl_down(s, off);
  __shared__ float w[4];
  if ((tid & 63) == 0) w[tid >> 6] = s;
  __syncthreads();
  if (tid == 0) {
    const float m = (w[0] + w[1] + w[2] + w[3]) * inv_count;
    out_loss[0] = m + 0.25f * m;  // q_latent + commitment * e_latent
  }
}

extern "C" void kernel_launch(void* const* d_in, const int* in_sizes, int n_in,
                              void* d_out, int out_size, void* d_ws,
                              size_t ws_size, hipStream_t stream) {
  const float* X = (const float*)d_in[0];  // [16,4096,256] fp32
  const float* E = (const float*)d_in[1];  // [1024,256] fp32
  float* out = (float*)d_out;              // [0]=loss, [1..]=quantized

  char* ws = (char*)d_ws;
  float* enormh = (float*)ws;                             // @0KB
  float* partials = (float*)(ws + 16 * 1024);             // @16KB
  unsigned char* Ef8 = (unsigned char*)(ws + 48 * 1024);  // @48KB (256KB)

  const int nrows = in_sizes[0] / DIM;  // 65536
  const int nb_main = nrows / BM;       // 512

  vq_prep_kernel<<<KCODES, 64, 0, stream>>>(E, enormh, Ef8);
  vq_fused_kernel<<<nb_main, 512, 0, stream>>>(X, E, Ef8, enormh, out + 1,
                                               partials);
  vq_finalize_kernel<<<1, 256, 0, stream>>>(partials, out, nb_main,
                                            1.0f / (float)in_sizes[0]);
}

// Round 17
// 74.321 us; speedup vs baseline: 1.3933x; 1.0204x over previous
//
#include <hip/hip_runtime.h>
#include <math.h>

#define DIM 256
#define KCODES 1024
#define NTILE 64        // 16-code tiles (4KB fp8 each)
#define BM 128          // rows per block (4 waves x 32 rows)
#define ESCALE 512.0f

typedef long i64;
typedef __attribute__((ext_vector_type(2))) long i64x2;
typedef __attribute__((ext_vector_type(4))) float f32x4;

// ---------------------------------------------------------------------------
// Prep: enormh[k] = -ESCALE*||e_k||^2/2, codebook scaled x512 -> fp8 e4m3 in
// MFMA B-fragment order:
// byte = (k>>4)*4096 + (ks>>1)*1024 + (lk*16+(k&15))*16 + (ks&1)*8 + (d&7)
// ---------------------------------------------------------------------------
__global__ __launch_bounds__(64) void vq_prep_kernel(
    const float* __restrict__ E, float* __restrict__ enormh,
    unsigned char* __restrict__ Ef8) {
  const int k = blockIdx.x;   // code
  const int t = threadIdx.x;  // dims 4t..4t+3
  const float4 v = *reinterpret_cast<const float4*>(&E[k * DIM + t * 4]);
  const int d0 = t * 4;
  const int ks = d0 >> 5;
  const int lk = (d0 >> 3) & 3;
  const int j = d0 & 7;  // 0 or 4
  const int lane16 = lk * 16 + (k & 15);
  const size_t byte = (size_t)((k >> 4) * 4096) + (size_t)((ks >> 1) * 1024) +
                      (size_t)(lane16 * 16) + (size_t)((ks & 1) * 8 + j);
  int p = __builtin_amdgcn_cvt_pk_fp8_f32(v.x * ESCALE, v.y * ESCALE, 0, 0);
  p = __builtin_amdgcn_cvt_pk_fp8_f32(v.z * ESCALE, v.w * ESCALE, p, 1);
  *reinterpret_cast<unsigned int*>(Ef8 + byte) = (unsigned int)p;
  float s = v.x * v.x + v.y * v.y + v.z * v.z + v.w * v.w;
#pragma unroll
  for (int off = 32; off >= 1; off >>= 1) s += __shfl_down(s, off);
  if (t == 0) enormh[k] = -0.5f * ESCALE * s;
}

__device__ inline i64 pack_fp8x8(const float4& a, const float4& b) {
  int lo = __builtin_amdgcn_cvt_pk_fp8_f32(a.x, a.y, 0, 0);
  lo = __builtin_amdgcn_cvt_pk_fp8_f32(a.z, a.w, lo, 1);
  int hi = __builtin_amdgcn_cvt_pk_fp8_f32(b.x, b.y, 0, 0);
  hi = __builtin_amdgcn_cvt_pk_fp8_f32(b.z, b.w, hi, 1);
  return ((i64)(unsigned int)hi << 32) | (i64)(unsigned int)lo;
}

// ---------------------------------------------------------------------------
// Fused main v17: 4-DEEP LDS ring + hand-counted vmcnt (T3/T4), fp8.
// 128 rows/block, 256 thr = 4 independent waves; wave w owns rows
// [w*32,w*32+32) x ALL 1024 codes. Each wave streams B through a PRIVATE
// 4-slot LDS ring (4KB/tile) via global_load_lds: issue(t+3) ->
// s_waitcnt vmcnt(12) -> consume(t). Window = 3 tiles (~1000cyc) >> loaded
// L2 latency; zero data VGPRs so the compiler cannot compress the pipeline.
// enorm table lives in LDS (lgkm domain) so no VMEM op disturbs the count.
// No __syncthreads in the hot loop.
// ---------------------------------------------------------------------------
__global__ __launch_bounds__(256, 2) void vq_fused_kernel(
    const float* __restrict__ X, const float* __restrict__ E,
    const unsigned char* __restrict__ Ef8, const float* __restrict__ enormh,
    float* __restrict__ outq, float* __restrict__ partials) {
  __shared__ __attribute__((aligned(16))) char ring[4][4][4096];  // 64KB
  __shared__ float enorm_s[KCODES];                               // 4KB
  __shared__ int idxs[BM];
  __shared__ float lred[4];

  const int tid = threadIdx.x;
  const int w = tid >> 6;  // wave 0..3 -> rows w*32 .. w*32+31
  const int lane = tid & 63;
  const int lr = lane & 15;
  const int lk = lane >> 4;
  const int row0 = blockIdx.x * BM;

  // ---- stage enorm table into LDS (1024 floats; threads 0..255 do 1 float4)
  {
    const float4 v = *reinterpret_cast<const float4*>(&enormh[tid * 4]);
    *reinterpret_cast<float4*>(&enorm_s[tid * 4]) = v;
  }

  // ---- A: 32 rows x 256 dims per wave, fp32 -> fp8 fragments (32 VGPRs)
  i64 Af[2][8];
#pragma unroll
  for (int mt = 0; mt < 2; ++mt) {
    const float* xrow = &X[(size_t)(row0 + w * 32 + mt * 16 + lr) * DIM];
#pragma unroll
    for (int ks = 0; ks < 8; ++ks) {
      const int k0 = ks * 32 + lk * 8;
      const float4 a = *reinterpret_cast<const float4*>(&xrow[k0]);
      const float4 b = *reinterpret_cast<const float4*>(&xrow[k0 + 4]);
      Af[mt][ks] = pack_fp8x8(a, b);
    }
  }

  float maxv[8];
  int mini[8];
#pragma unroll
  for (int i = 0; i < 8; ++i) { maxv[i] = -INFINITY; mini[i] = 0; }

  const char* efsrc = reinterpret_cast<const char*>(Ef8) + lane * 16;
  char* ringw = &ring[w][0][0];

  // barrier: enorm_s visible; also drains A/enorm VMEM so vmcnt count is clean
  __syncthreads();

#define ISSUE(T)                                                              \
  {                                                                           \
    const char* src_ = efsrc + (size_t)(T) * 4096;                            \
    char* dst_ = ringw + ((T) & 3) * 4096;                                    \
    _Pragma("unroll") for (int i_ = 0; i_ < 4; ++i_)                          \
        __builtin_amdgcn_global_load_lds(                                     \
            (const __attribute__((address_space(1))) unsigned int*)(src_ +    \
                                                                    i_ *      \
                                                                        1024),\
            (__attribute__((address_space(3))) unsigned int*)(dst_ +          \
                                                              i_ * 1024 +     \
                                                              lane * 16),     \
            16, 0, 0);                                                        \
  }

#define CONSUME(T)                                                            \
  {                                                                           \
    const char* cbuf_ = ringw + ((T) & 3) * 4096;                             \
    const float en_ = enorm_s[(T) * 16 + lr];                                 \
    f32x4 acc0, acc1;                                                         \
    acc0[0] = en_; acc0[1] = en_; acc0[2] = en_; acc0[3] = en_;               \
    acc1 = acc0;                                                              \
    _Pragma("unroll") for (int p_ = 0; p_ < 4; ++p_) {                        \
      const i64x2 bv_ =                                                       \
          *reinterpret_cast<const i64x2*>(cbuf_ + p_ * 1024 + lane * 16);     \
      acc0 = __builtin_amdgcn_mfma_f32_16x16x32_fp8_fp8(Af[0][2 * p_],        \
                                                        bv_[0], acc0, 0,0,0); \
      acc1 = __builtin_amdgcn_mfma_f32_16x16x32_fp8_fp8(Af[1][2 * p_],        \
                                                        bv_[0], acc1, 0,0,0); \
      acc0 = __builtin_amdgcn_mfma_f32_16x16x32_fp8_fp8(Af[0][2 * p_ + 1],    \
                                                        bv_[1], acc0, 0,0,0); \
      acc1 = __builtin_amdgcn_mfma_f32_16x16x32_fp8_fp8(Af[1][2 * p_ + 1],    \
                                                        bv_[1], acc1, 0,0,0); \
    }                                                                         \
    const int code_ = (T) * 16 + lr;                                          \
    _Pragma("unroll") for (int r_ = 0; r_ < 4; ++r_) {                        \
      if (acc0[r_] > maxv[r_]) { maxv[r_] = acc0[r_]; mini[r_] = code_; }     \
      if (acc1[r_] > maxv[4 + r_]) {                                          \
        maxv[4 + r_] = acc1[r_]; mini[4 + r_] = code_;                        \
      }                                                                       \
    }                                                                         \
  }

  // prologue: fill 3 ring slots
  ISSUE(0);
  ISSUE(1);
  ISSUE(2);

  // main loop: issue(t+3), wait until only 3 tiles (12 loads) outstanding,
  // consume(t). unroll 4 -> ring-slot addressing is compile-time static.
#pragma unroll 4
  for (int t = 0; t < NTILE - 4; ++t) {
    ISSUE(t + 3);
    asm volatile("s_waitcnt vmcnt(12)" ::: "memory");
    __builtin_amdgcn_sched_barrier(0);
    CONSUME(t);
  }
  // t = 60: last issue (tile 63)
  ISSUE(63);
  asm volatile("s_waitcnt vmcnt(12)" ::: "memory");
  __builtin_amdgcn_sched_barrier(0);
  CONSUME(60);
  asm volatile("s_waitcnt vmcnt(8)" ::: "memory");
  __builtin_amdgcn_sched_barrier(0);
  CONSUME(61);
  asm volatile("s_waitcnt vmcnt(4)" ::: "memory");
  __builtin_amdgcn_sched_barrier(0);
  CONSUME(62);
  asm volatile("s_waitcnt vmcnt(0)" ::: "memory");
  __builtin_amdgcn_sched_barrier(0);
  CONSUME(63);
#undef ISSUE
#undef CONSUME

  // reduce across the 16 code-lanes (lr); max score, tie -> lower code
#pragma unroll
  for (int off = 1; off < 16; off <<= 1) {
#pragma unroll
    for (int ri = 0; ri < 8; ++ri) {
      const float ov = __shfl_xor(maxv[ri], off);
      const int oi = __shfl_xor(mini[ri], off);
      if (ov > maxv[ri] || (ov == maxv[ri] && oi < mini[ri])) {
        maxv[ri] = ov; mini[ri] = oi;
      }
    }
  }
  if (lr == 0) {
#pragma unroll
    for (int mt = 0; mt < 2; ++mt)
#pragma unroll
      for (int r = 0; r < 4; ++r)
        idxs[w * 32 + mt * 16 + lk * 4 + r] = mini[mt * 4 + r];
  }
  __syncthreads();

  // ---- fused epilogue: gather + STE + loss partial, exact fp32.
  // two 64-row halves; 4 threads per row, 64 dims each, coalesced float4.
  float lsum = 0.0f;
#pragma unroll
  for (int half = 0; half < 2; ++half) {
    const int er = half * 64 + (tid >> 2);
    const int eq = tid & 3;
    const int code = idxs[er];
    const float* erow = &E[(size_t)code * DIM];
    const float* xrow = &X[(size_t)(row0 + er) * DIM];
    float* orow = &outq[(size_t)(row0 + er) * DIM];
#pragma unroll
    for (int j = 0; j < 16; ++j) {
      const int d = j * 16 + eq * 4;
      const float4 e = *reinterpret_cast<const float4*>(&erow[d]);
      const float4 x = *reinterpret_cast<const float4*>(&xrow[d]);
      const float dx0 = e.x - x.x, dx1 = e.y - x.y;
      const float dx2 = e.z - x.z, dx3 = e.w - x.w;
      float4 o;
      o.x = x.x + dx0; o.y = x.y + dx1; o.z = x.z + dx2; o.w = x.w + dx3;
      *reinterpret_cast<float4*>(&orow[d]) = o;
      lsum += dx0 * dx0 + dx1 * dx1 + dx2 * dx2 + dx3 * dx3;
    }
  }
#pragma unroll
  for (int off = 32; off >= 1; off >>= 1) lsum += __shfl_down(lsum, off);
  if (lane == 0) lred[w] = lsum;
  __syncthreads();
  if (tid == 0)
    partials[blockIdx.x] = lred[0] + lred[1] + lred[2] + lred[3];
}

// ---------------------------------------------------------------------------
// Deterministic loss reduction
// ---------------------------------------------------------------------------
__global__ __launch_bounds__(256) void vq_finalize_kernel(
    const float* __restrict__ partials, float* __restrict__ out_loss,
    int nparts, float inv_count) {
  const int tid = threadIdx.x;
  float s = 0.0f;
  for (int i = tid; i < nparts; i += 256) s += partials[i];
#pragma unroll
  for (int off = 32; off >= 1; off >>= 1) s += __shfl_down(s, off);
  __shared__ float w[4];
  if ((tid & 63) == 0) w[tid >> 6] = s;
  __syncthreads();
  if (tid == 0) {
    const float m = (w[0] + w[1] + w[2] + w[3]) * inv_count;
    out_loss[0] = m + 0.25f * m;  // q_latent + commitment * e_latent
  }
}

extern "C" void kernel_launch(void* const* d_in, const int* in_sizes, int n_in,
                              void* d_out, int out_size, void* d_ws,
                              size_t ws_size, hipStream_t stream) {
  const float* X = (const float*)d_in[0];  // [16,4096,256] fp32
  const float* E = (const float*)d_in[1];  // [1024,256] fp32
  float* out = (float*)d_out;              // [0]=loss, [1..]=quantized

  char* ws = (char*)d_ws;
  float* enormh = (float*)ws;                             // @0KB
  float* partials = (float*)(ws + 16 * 1024);             // @16KB
  unsigned char* Ef8 = (unsigned char*)(ws + 48 * 1024);  // @48KB (256KB)

  const int nrows = in_sizes[0] / DIM;  // 65536
  const int nb_main = nrows / BM;       // 512

  vq_prep_kernel<<<KCODES, 64, 0, stream>>>(E, enormh, Ef8);
  vq_fused_kernel<<<nb_main, 256, 0, stream>>>(X, E, Ef8, enormh, out + 1,
                                               partials);
  vq_finalize_kernel<<<1, 256, 0, stream>>>(partials, out, nb_main,
                                            1.0f / (float)in_sizes[0]);
}